// Round 8
// baseline (144.347 us; speedup 1.0000x reference)
//
#include <hip/hip_runtime.h>

// Cubic B-spline prefilter (Unser), periodic, axes 2,3,4 of (2,3,160,160,160) fp32.
//
// Three IN-PLACE pass kernels (no d_ws): replay working set = x + out = 196 MB
// <= 256 MB Infinity Cache -> L3-resident at steady state (the R2/R3 in-place
// pipelines showed pass_d2 at ~10-14 us; the R4-R6 ws pipeline (294 MB) thrashed
// L3 and pinned pass_d2 at ~70 us of cold HBM reads).
//
// Each block stages a tile containing EVERYTHING it reads (full filter axis in
// LDS) -> in-place is race-free. Sweeps: chunk-20 per thread, KW=16 truncated
// causal warm-up + T-trick anticausal init (state ~30 VGPR, no spill;
// __launch_bounds__(.,8) caps VGPR at 64, LDS 40 KB x 4 blocks = 160 KB/CU,
// 32 waves/CU).
//
//   k_d2: tile [160 rows][64 cols], row stride 160^2.  width-64 rows => zero
//         bank conflicts with NO swizzle (fixed-r access = banks 0..31 x2).
//   k_d3: tile [160 rows][32 cols], row stride 160.
//   k_d4: tile [64 lines][160], contiguous; XOR swizzle m^(line&31) for the
//         along-line walks (64 lanes = 64 lines at same col otherwise).

#define NAX  160
#define PLN  25600                        // 160*160
#define VOL  4096000                      // 160*PLN
#define ZP   (-0.26794919243112270647f)   // sqrt(3)-2
#define KW   16                           // truncated warm-up (z^16 ~ 7.4e-10)

// ---------------- K1: axis d2 (in -> out) -----------------------------------
__global__ __launch_bounds__(512, 8)
void k_d2(const float* __restrict__ in, float* __restrict__ out)
{
    __shared__ float T[NAX * 64];          // 40 KB
    const float z = ZP;
    const int t    = threadIdx.x;
    const int lane = t & 63, wv = t >> 6;  // col, wave(=chunk)
    const int g  = blockIdx.x;             // 0..2399
    const int v  = g / 400;                // volume 0..5
    const int i0 = (g - v * 400) * 64;     // col base in flattened (d3,d4)
    const float* src = in  + (size_t)v * VOL + i0;
    float*       dst = out + (size_t)v * VOL + i0;

    // load tile: wave wv covers rows wv, wv+8, ... (256 B contiguous each)
    #pragma unroll
    for (int k = 0; k < 20; ++k) {
        const int r = wv + 8 * k;
        T[r * 64 + lane] = src[(size_t)r * PLN + lane];
    }
    __syncthreads();

    const int c = lane, n0 = wv * 20;
    float st = 0.f;
    #pragma unroll
    for (int s = 0; s < KW; ++s) {         // causal warm-up (wraps)
        int r = n0 - KW + s; if (r < 0) r += NAX;
        st = fmaf(z, st, 6.0f * T[r * 64 + c]);
    }
    float f[20];
    #pragma unroll
    for (int s = 0; s < 20; ++s) {         // causal outputs
        st = fmaf(z, st, 6.0f * T[(n0 + s) * 64 + c]);
        f[s] = st;
    }
    float Ta = 0.f, zp = z;                // T-trick anticausal init
    #pragma unroll
    for (int k = 0; k < KW; ++k) {
        int r = n0 + 20 + k; if (r >= NAX) r -= NAX;
        st = fmaf(z, st, 6.0f * T[r * 64 + c]);
        Ta = fmaf(zp, st, Ta);
        zp *= z;                           // constant-folds under unroll
    }
    float sm = -Ta;                        // anticausal sweep, direct store
    #pragma unroll
    for (int s = 19; s >= 0; --s) {
        sm = z * (sm - f[s]);
        dst[(size_t)(n0 + s) * PLN + c] = sm;
    }
}

// ---------------- K2: axis d3 (in-place) ------------------------------------
__global__ __launch_bounds__(256, 8)
void k_d3(float* __restrict__ buf)
{
    __shared__ float T[NAX * 32];          // 20 KB
    const float z = ZP;
    const int t  = threadIdx.x;
    const int g  = blockIdx.x;             // 0..4799
    const int p  = g / 5;                  // d2-slice 0..959
    const int c0 = (g - p * 5) * 32;       // d4 col base
    float* base = buf + (size_t)p * PLN + c0;

    #pragma unroll
    for (int k = 0; k < 20; ++k) {         // load 160x32
        const int idx = t + 256 * k;       // 0..5119 = r*32+c
        const int r = idx >> 5, c = idx & 31;
        T[idx] = base[r * NAX + c];
    }
    __syncthreads();

    const int c = t & 31, q = t >> 5;      // col, chunk 0..7
    const int n0 = q * 20;
    float st = 0.f;
    #pragma unroll
    for (int s = 0; s < KW; ++s) {
        int r = n0 - KW + s; if (r < 0) r += NAX;
        st = fmaf(z, st, 6.0f * T[r * 32 + c]);
    }
    float f[20];
    #pragma unroll
    for (int s = 0; s < 20; ++s) {
        st = fmaf(z, st, 6.0f * T[(n0 + s) * 32 + c]);
        f[s] = st;
    }
    float Ta = 0.f, zp = z;
    #pragma unroll
    for (int k = 0; k < KW; ++k) {
        int r = n0 + 20 + k; if (r >= NAX) r -= NAX;
        st = fmaf(z, st, 6.0f * T[r * 32 + c]);
        Ta = fmaf(zp, st, Ta);
        zp *= z;
    }
    float sm = -Ta;
    #pragma unroll
    for (int s = 19; s >= 0; --s) {
        sm = z * (sm - f[s]);
        base[(n0 + s) * NAX + c] = sm;     // 128 B contiguous per half-wave
    }
}

// ---------------- K3: axis d4 (in-place) ------------------------------------
__global__ __launch_bounds__(512, 8)
void k_d4(float* __restrict__ buf)
{
    __shared__ float T[64 * NAX];          // 40 KB
    const float z = ZP;
    const int t = threadIdx.x;
    float* base = buf + (size_t)blockIdx.x * (64 * NAX);

    #pragma unroll
    for (int k = 0; k < 20; ++k) {         // contiguous block load, swizzled LDS
        const int idx = t + 512 * k;       // 0..10239
        const int rr = idx / NAX, m = idx - rr * NAX;
        T[rr * NAX + (m ^ (rr & 31))] = base[idx];
    }
    __syncthreads();

    const int rr = t & 63, q = t >> 6;     // line, chunk 0..7
    const int n0 = q * 20, xo = rr & 31;
    const float* Tr = T + rr * NAX;
    float st = 0.f;
    #pragma unroll
    for (int s = 0; s < KW; ++s) {
        int m = n0 - KW + s; if (m < 0) m += NAX;
        st = fmaf(z, st, 6.0f * Tr[m ^ xo]);
    }
    float f[20];
    #pragma unroll
    for (int s = 0; s < 20; ++s) {
        st = fmaf(z, st, 6.0f * Tr[(n0 + s) ^ xo]);
        f[s] = st;
    }
    float Ta = 0.f, zp = z;
    #pragma unroll
    for (int k = 0; k < KW; ++k) {
        int m = n0 + 20 + k; if (m >= NAX) m -= NAX;
        st = fmaf(z, st, 6.0f * Tr[m ^ xo]);
        Ta = fmaf(zp, st, Ta);
        zp *= z;
    }
    float sm = -Ta;
    #pragma unroll
    for (int s = 19; s >= 0; --s) { sm = z * (sm - f[s]); f[s] = sm; }
    __syncthreads();                       // all T reads done before overwrite
    float* Tw = T + rr * NAX;
    #pragma unroll
    for (int s = 0; s < 20; ++s)
        Tw[(n0 + s) ^ xo] = f[s];
    __syncthreads();

    #pragma unroll
    for (int k = 0; k < 20; ++k) {         // contiguous block store
        const int idx = t + 512 * k;
        const int rr2 = idx / NAX, m = idx - rr2 * NAX;
        base[idx] = T[rr2 * NAX + (m ^ (rr2 & 31))];
    }
}

extern "C" void kernel_launch(void* const* d_in, const int* in_sizes, int n_in,
                              void* d_out, int out_size, void* d_ws, size_t ws_size,
                              hipStream_t stream) {
    (void)in_sizes; (void)n_in; (void)d_ws; (void)ws_size; (void)out_size;
    const float* x = (const float*)d_in[0];
    float* out = (float*)d_out;

    k_d2<<<2400, 512, 0, stream>>>(x, out);   // d2: x -> out
    k_d3<<<4800, 256, 0, stream>>>(out);      // d3: in-place
    k_d4<<<2400, 512, 0, stream>>>(out);      // d4: in-place
}

// Round 9
// 139.248 us; speedup vs baseline: 1.0366x; 1.0366x over previous
//
#include <hip/hip_runtime.h>

// Cubic B-spline prefilter (Unser), periodic, axes 2,3,4 of (2,3,160,160,160) fp32.
//
// Three IN-PLACE passes (no d_ws): replay working set = x + out = 196 MB fits
// the 256 MB Infinity Cache -> L3-resident steady state.
//
// REGISTER RULE (from R4-R7 forensics): __launch_bounds__ waves/EU caps the
// UNIFIED VGPR+AGPR budget (2048/waves). At 8 waves/EU the 64-reg cap forced
// f[20] into memory scratch (R7 k_d4: WRITE 2.5x ideal). At 6 waves/EU the
// ~85-reg budget holds chunk-20 state (~55 live) with zero scratch.
//
// k_d2 / k_d3: direct-global chunk-20 sweeps, NO LDS. 512 thr = 64 lines x
//   8 chunks; a block owns all chunks of its lines, so one barrier between
//   compute and store makes in-place race-free. Reads are 256 B/wave bursts;
//   the 2.6x row re-reads (warm/tail overlap) hit L1/L2 block-locally.
// k_d4: lines run along memory -> LDS staging for coalescing (R7 structure,
//   XOR swizzle, validated conflict-free), now at (512,6).
//
// Sweep numerics (validated R5-R7, absmax 0.125): causal warm-up KW=16
// (z^16 ~ 7.4e-10), 20 outputs, T-trick anticausal init over 16-row tail.

#define NAX  160
#define PLN  25600                        // 160*160
#define VOL  4096000                      // 160*PLN
#define ZP   (-0.26794919243112270647f)   // sqrt(3)-2
#define KW   16

// ---- generic strided-axis pass: S = element stride along the filter axis,
//      line L -> base = (L/LDIV)*OSTR + (L%LDIV) ------------------------------
template <int S, int LDIV, int OSTR, bool INPLACE>
__global__ __launch_bounds__(512, 6)
void pass_ax(const float* __restrict__ in, float* __restrict__ out)
{
    const float z = ZP;
    const int t    = threadIdx.x;
    const int lane = t & 63, q = t >> 6;          // line-lane, chunk 0..7
    const int L = blockIdx.x * 64 + lane;         // line id
    const int o = L / LDIV, i = L - o * LDIV;
    const size_t base = (size_t)o * OSTR + i;
    const float* src = in + base;
    const int n0 = q * 20;

    // causal warm-up (wraps)
    float st = 0.f;
    #pragma unroll
    for (int s = 0; s < KW; ++s) {
        int r = n0 - KW + s; if (r < 0) r += NAX;
        st = fmaf(z, st, 6.0f * src[(size_t)r * S]);
    }
    // causal outputs (n0+19 <= 159, never wraps)
    float f[20];
    #pragma unroll
    for (int s = 0; s < 20; ++s) {
        st = fmaf(z, st, 6.0f * src[(size_t)(n0 + s) * S]);
        f[s] = st;
    }
    // tail: extend c+ and accumulate T => c-(n0+20) = -T
    float Ta = 0.f, zp = z;
    #pragma unroll
    for (int k = 0; k < KW; ++k) {
        int r = n0 + 20 + k; if (r >= NAX) r -= NAX;
        st = fmaf(z, st, 6.0f * src[(size_t)r * S]);
        Ta = fmaf(zp, st, Ta);
        zp *= z;                                  // constant-folds
    }
    // anticausal sweep (in registers)
    float sm = -Ta;
    #pragma unroll
    for (int s = 19; s >= 0; --s) { sm = z * (sm - f[s]); f[s] = sm; }

    if (INPLACE) __syncthreads();                 // all reads before any write
    float* dst = out + base;
    #pragma unroll
    for (int s = 0; s < 20; ++s)
        dst[(size_t)(n0 + s) * S] = f[s];
}

// ---- axis d4: contiguous lines, LDS-staged (R7 structure, (512,6)) ---------
__global__ __launch_bounds__(512, 6)
void k_d4(float* __restrict__ buf)
{
    __shared__ float T[64 * NAX];          // 40 KB
    const float z = ZP;
    const int t = threadIdx.x;
    float* base = buf + (size_t)blockIdx.x * (64 * NAX);

    #pragma unroll
    for (int k = 0; k < 20; ++k) {         // contiguous block load, swizzled LDS
        const int idx = t + 512 * k;       // 0..10239
        const int rr = idx / NAX, m = idx - rr * NAX;
        T[rr * NAX + (m ^ (rr & 31))] = base[idx];
    }
    __syncthreads();

    const int rr = t & 63, q = t >> 6;     // line, chunk 0..7
    const int n0 = q * 20, xo = rr & 31;
    const float* Tr = T + rr * NAX;
    float st = 0.f;
    #pragma unroll
    for (int s = 0; s < KW; ++s) {
        int m = n0 - KW + s; if (m < 0) m += NAX;
        st = fmaf(z, st, 6.0f * Tr[m ^ xo]);
    }
    float f[20];
    #pragma unroll
    for (int s = 0; s < 20; ++s) {
        st = fmaf(z, st, 6.0f * Tr[(n0 + s) ^ xo]);
        f[s] = st;
    }
    float Ta = 0.f, zp = z;
    #pragma unroll
    for (int k = 0; k < KW; ++k) {
        int m = n0 + 20 + k; if (m >= NAX) m -= NAX;
        st = fmaf(z, st, 6.0f * Tr[m ^ xo]);
        Ta = fmaf(zp, st, Ta);
        zp *= z;
    }
    float sm = -Ta;
    #pragma unroll
    for (int s = 19; s >= 0; --s) { sm = z * (sm - f[s]); f[s] = sm; }
    __syncthreads();                       // all T reads done before overwrite
    float* Tw = T + rr * NAX;
    #pragma unroll
    for (int s = 0; s < 20; ++s)
        Tw[(n0 + s) ^ xo] = f[s];
    __syncthreads();

    #pragma unroll
    for (int k = 0; k < 20; ++k) {         // contiguous block store
        const int idx = t + 512 * k;
        const int rr2 = idx / NAX, m = idx - rr2 * NAX;
        base[idx] = T[rr2 * NAX + (m ^ (rr2 & 31))];
    }
}

extern "C" void kernel_launch(void* const* d_in, const int* in_sizes, int n_in,
                              void* d_out, int out_size, void* d_ws, size_t ws_size,
                              hipStream_t stream) {
    (void)in_sizes; (void)n_in; (void)d_ws; (void)ws_size; (void)out_size;
    const float* x = (const float*)d_in[0];
    float* out = (float*)d_out;

    // d2: lines indexed (v, i): base = v*VOL + i, stride PLN.  x -> out.
    pass_ax<PLN, PLN, VOL, false><<<2400, 512, 0, stream>>>(x, out);
    // d3: lines indexed (p, c): base = p*PLN + c, stride NAX.  in-place.
    pass_ax<NAX, NAX, PLN, true><<<2400, 512, 0, stream>>>(out, out);
    // d4: contiguous lines, in-place.
    k_d4<<<2400, 512, 0, stream>>>(out);
}

// Round 10
// 78.579 us; speedup vs baseline: 1.8370x; 1.7721x over previous
//
#include <hip/hip_runtime.h>

// Cubic B-spline prefilter (Unser), periodic, axes 2,3,4 of (2,3,160,160,160) fp32.
//
// Pipeline = R5's replay winner (93.8 us), surgically improved:
//   pass_d2   : VERBATIM R5 kernel (scalar, 4x40-chunk, cp[56]->AGPR, (256,5)).
//               Only variant that ever showed WRITE==96000 KB (no spill). x -> ws.
//   slab_d3d4 : 40x160 slab per 320-thr block (R5 structure) with:
//               (a) T-trick anticausal init in BOTH phases (-16 regs, -32 VALU/thr;
//                   slab was 48% VALUBusy),
//               (b) d4-phase remap rr=tid>>3,mq=tid&7 -> wave lanes spread over
//                   8 rows x 8 chunks, kills the measured 1.4M bank conflicts,
//               (c) NT final store: out bypasses L3 so x+ws (196 MB) stay fully
//                   L3-resident across replays (out is write-once, never read --
//                   the cheapest thing to spill),
//               (d) XCD-coherent block map: the 4 slabs of a plane (sharing +-16
//                   row halos) land on the same XCD's L2.
// Fallback (ws too small): R3-validated in-place full-plane kernel.

#define NAX   160
#define PLN   25600      // 160*160
#define VOL   4096000    // 160*PLN
#define ZP    (-0.26794919243112270647f)   // sqrt(3)-2
#define KW    16         // truncated warm-up (z^16 ~ 7.4e-10)

// ---------------- Kernel A: axis-2 (VERBATIM R5 winner) ---------------------
__global__ __launch_bounds__(256, 5)
void pass_d2(const float* __restrict__ in, float* __restrict__ out)
{
    const float z = ZP;
    const int l     = threadIdx.x & 63;
    const int chunk = threadIdx.x >> 6;
    const int L = blockIdx.x * 64 + l;
    const int v = L / PLN;
    const int i = L - v * PLN;
    const float* src = in  + (size_t)v * VOL + i;
    float*       dst = out + (size_t)v * VOL + i;
    const int n0 = chunk * 40;

    float st = 0.0f;
    #pragma unroll
    for (int s = 0; s < KW; ++s) {
        int r = n0 - KW + s; if (r < 0) r += NAX;
        st = fmaf(z, st, 6.0f * src[(size_t)r * PLN]);
    }
    float cp[56];
    #pragma unroll
    for (int s = 0; s < 56; ++s) {
        int r = n0 + s; if (r >= NAX) r -= NAX;
        st = fmaf(z, st, 6.0f * src[(size_t)r * PLN]);
        cp[s] = st;
    }
    float sm = 0.0f;
    #pragma unroll
    for (int s = 55; s >= 40; --s) sm = z * (sm - cp[s]);
    #pragma unroll
    for (int s = 39; s >= 0; --s) {
        sm = z * (sm - cp[s]);
        dst[(size_t)(n0 + s) * PLN] = sm;
    }
}

// ---------------- Kernel B: fused axes 3+4, 40-row slab ---------------------
__device__ __forceinline__ int swz(int r, int c) {
    return r * NAX + (c ^ (r & 31));
}

__global__ __launch_bounds__(320, 6)
void slab_d3d4(const float* __restrict__ src, float* __restrict__ dst)
{
    __shared__ float Y[40 * NAX];        // 25.6 KB exchange buffer
    const float z = ZP;
    const int tid = threadIdx.x;         // 0..319

    // XCD-coherent decode: b = (p%8) + 8*q + 32*(p/8)  (bijective, 3840 blocks)
    // -> all 4 slabs of plane p share blockIdx%8, i.e. one XCD's L2.
    const int b   = blockIdx.x;
    const int q   = (b >> 3) & 3;        // slab 0..3
    const int p   = ((b >> 5) << 3) + (b & 7);   // plane 0..959
    const int R0  = 40 * q;
    const float* pin  = src + (size_t)p * PLN;
    float*       pout = dst + (size_t)p * PLN;

    float f[20];

    // ---- d3: thread (c, h) -> rows R0+20h .. R0+20h+19, column c -----------
    {
        const int c  = tid % NAX;
        const int h  = tid / NAX;        // 0..1
        const int n0 = R0 + 20 * h;
        float st = 0.0f;
        #pragma unroll
        for (int s = 0; s < KW; ++s) {   // causal warm-up (wraps)
            int r = n0 - KW + s; if (r < 0) r += NAX;
            st = fmaf(z, st, 6.0f * pin[r * NAX + c]);
        }
        #pragma unroll
        for (int s = 0; s < 20; ++s) {   // causal outputs
            st = fmaf(z, st, 6.0f * pin[(n0 + s) * NAX + c]);
            f[s] = st;
        }
        float Ta = 0.0f, zp = z;         // T-trick: c-(n0+20) = -T
        #pragma unroll
        for (int k = 0; k < KW; ++k) {
            int r = n0 + 20 + k; if (r >= NAX) r -= NAX;
            st = fmaf(z, st, 6.0f * pin[r * NAX + c]);
            Ta = fmaf(zp, st, Ta);
            zp *= z;                     // constant-folds under unroll
        }
        float sm = -Ta;
        #pragma unroll
        for (int s = 19; s >= 0; --s) { sm = z * (sm - f[s]); f[s] = sm; }

        const int lr0 = 20 * h;          // publish slab rows (local 0..39)
        #pragma unroll
        for (int s = 0; s < 20; ++s)
            Y[swz(lr0 + s, c)] = f[s];
    }
    __syncthreads();

    // ---- d4: thread (rr, mq) -> slab row rr, columns 20mq .. 20mq+19 -------
    // remap rr=tid>>3, mq=tid&7: each wave = 8 rows x 8 chunks -> banks spread
    {
        const int rr = tid >> 3;         // 0..39
        const int mq = tid & 7;          // 0..7
        const int m0 = 20 * mq;
        float st = 0.0f;
        #pragma unroll
        for (int s = 0; s < KW; ++s) {
            int cc = m0 - KW + s; if (cc < 0) cc += NAX;
            st = fmaf(z, st, 6.0f * Y[swz(rr, cc)]);
        }
        #pragma unroll
        for (int s = 0; s < 20; ++s) {
            st = fmaf(z, st, 6.0f * Y[swz(rr, m0 + s)]);
            f[s] = st;
        }
        float Ta = 0.0f, zp = z;
        #pragma unroll
        for (int k = 0; k < KW; ++k) {
            int cc = m0 + 20 + k; if (cc >= NAX) cc -= NAX;
            st = fmaf(z, st, 6.0f * Y[swz(rr, cc)]);
            Ta = fmaf(zp, st, Ta);
            zp *= z;
        }
        float sm = -Ta;
        #pragma unroll
        for (int s = 19; s >= 0; --s) { sm = z * (sm - f[s]); f[s] = sm; }

        __syncthreads();                 // ALL Y reads done before overwrite
        #pragma unroll
        for (int s = 0; s < 20; ++s)
            Y[swz(rr, m0 + s)] = f[s];
    }
    __syncthreads();

    // ---- coalesced NT store (out never re-read: keep it OUT of L3 so x+ws
    //      stay resident) -----------------------------------------------------
    #pragma unroll
    for (int k = 0; k < 20; ++k) {
        const int idx = tid + 320 * k;
        const int lr  = idx / NAX;
        const int c   = idx - lr * NAX;
        __builtin_nontemporal_store(Y[swz(lr, c)], &pout[(R0 + lr) * NAX + c]);
    }
}

// ---------------- Fallback: R3-validated in-place full-plane kernel ---------
__global__ __launch_bounds__(640, 2)
void pass_d3d4(float* __restrict__ buf)
{
    __shared__ float P[PLN];
    const float z = ZP;
    const int tid = threadIdx.x;
    float* plane = buf + (size_t)blockIdx.x * PLN;

    const int c  = tid % NAX;
    const int tq = tid / NAX;
    const int n0 = tq * 40;

    #pragma unroll
    for (int k = 0; k < 40; ++k) {
        const int r = 4 * k + tq;
        P[swz(r, c)] = plane[r * NAX + c];
    }
    __syncthreads();

    float f[40];
    {
        float st = 0.0f;
        #pragma unroll
        for (int s = 0; s < KW; ++s) {
            int r = n0 - KW + s; if (r < 0) r += NAX;
            st = fmaf(z, st, 6.0f * P[swz(r, c)]);
        }
        #pragma unroll
        for (int s = 0; s < 40; ++s) {
            st = fmaf(z, st, 6.0f * P[swz(n0 + s, c)]);
            f[s] = st;
        }
        __syncthreads();
        #pragma unroll
        for (int s = 0; s < 40; ++s) P[swz(n0 + s, c)] = f[s];
        __syncthreads();
        float sm = 0.0f;
        #pragma unroll
        for (int s = KW - 1; s >= 0; --s) {
            int r = n0 + 40 + s; if (r >= NAX) r -= NAX;
            sm = z * (sm - P[swz(r, c)]);
        }
        __syncthreads();
        #pragma unroll
        for (int s = 39; s >= 0; --s) { sm = z * (sm - f[s]); P[swz(n0 + s, c)] = sm; }
        __syncthreads();
    }
    {
        const int rr = c;
        float st = 0.0f;
        #pragma unroll
        for (int s = 0; s < KW; ++s) {
            int cc = n0 - KW + s; if (cc < 0) cc += NAX;
            st = fmaf(z, st, 6.0f * P[swz(rr, cc)]);
        }
        #pragma unroll
        for (int s = 0; s < 40; ++s) {
            st = fmaf(z, st, 6.0f * P[swz(rr, n0 + s)]);
            f[s] = st;
        }
        __syncthreads();
        #pragma unroll
        for (int s = 0; s < 40; ++s) P[swz(rr, n0 + s)] = f[s];
        __syncthreads();
        float sm = 0.0f;
        #pragma unroll
        for (int s = KW - 1; s >= 0; --s) {
            int cc = n0 + 40 + s; if (cc >= NAX) cc -= NAX;
            sm = z * (sm - P[swz(rr, cc)]);
        }
        __syncthreads();
        #pragma unroll
        for (int s = 39; s >= 0; --s) { sm = z * (sm - f[s]); P[swz(rr, n0 + s)] = sm; }
        __syncthreads();
    }
    #pragma unroll
    for (int k = 0; k < 40; ++k) {
        const int r = 4 * k + tq;
        plane[r * NAX + c] = P[swz(r, c)];
    }
}

extern "C" void kernel_launch(void* const* d_in, const int* in_sizes, int n_in,
                              void* d_out, int out_size, void* d_ws, size_t ws_size,
                              hipStream_t stream) {
    (void)in_sizes; (void)n_in; (void)out_size;
    const float* x = (const float*)d_in[0];
    float* out = (float*)d_out;
    float* ws  = (float*)d_ws;

    const size_t need = (size_t)6 * VOL * sizeof(float);   // 98.3 MB intermediate
    if (ws_size >= need) {
        pass_d2  <<<2400, 256, 0, stream>>>(x, ws);    // in -> ws
        slab_d3d4<<<3840, 320, 0, stream>>>(ws, out);  // ws -> out (disjoint)
    } else {
        pass_d2  <<<2400, 256, 0, stream>>>(x, out);
        pass_d3d4<<<960,  640, 0, stream>>>(out);      // validated fallback
    }
}

// Round 11
// 70.805 us; speedup vs baseline: 2.0386x; 1.1098x over previous
//
#include <hip/hip_runtime.h>

// Cubic B-spline prefilter (Unser), periodic, axes 2,3,4 of (2,3,160,160,160) fp32.
//
// Pipeline (R9 winner, 78.6 us, with pass_d2 replaced):
//   k_d2s     : axis-2 via LDS-staged [160 x 64] tile (40 KB). 512 thr:
//               coalesced load (20x 256B/wave rows), 1 barrier, 8x chunk-20
//               register sweeps reading LDS (1.0x read amp -- warm+tail from
//               LDS), direct reg->global stores (out-of-place => no 2nd
//               barrier). State ~35 reg, (512,6) cap 85 -> no spill, 3
//               blocks/CU = 24 waves/CU. Replaces the latency-bound scalar
//               pass_d2 (72 stride-100KB loads, serial chain, AGPR shuffles,
//               1.8x amp, 50% occ). x -> ws.
//   slab_d3d4 : VERBATIM R9 (T-trick, d4 remap rr=tid>>3, NT final store so
//               out stays out of L3, XCD-coherent block map). ws -> out.
// Fallback (ws too small): R3-validated in-place full-plane kernel.

#define NAX   160
#define PLN   25600      // 160*160
#define VOL   4096000    // 160*PLN
#define ZP    (-0.26794919243112270647f)   // sqrt(3)-2
#define KW    16         // truncated warm-up (z^16 ~ 7.4e-10)

// ---------------- Kernel A: axis-2, LDS-staged full-axis tile ---------------
__global__ __launch_bounds__(512, 6)
void k_d2s(const float* __restrict__ in, float* __restrict__ out)
{
    __shared__ float T[NAX * 64];          // 40 KB, layout [row][64]
    const float z = ZP;
    const int t    = threadIdx.x;
    const int lane = t & 63, wv = t >> 6;  // col-in-tile, wave(=chunk) 0..7
    const int g  = blockIdx.x;             // 0..2399
    const int v  = g / 400;                // volume (b,c) 0..5
    const int i0 = (g - v * 400) * 64;     // col base in flattened (d3,d4)
    const float* src = in  + (size_t)v * VOL + i0;
    float*       dst = out + (size_t)v * VOL + i0;

    // ---- load tile: wave wv covers rows wv, wv+8, ..., each 256 B contiguous
    #pragma unroll
    for (int k = 0; k < 20; ++k) {
        const int r = wv + 8 * k;
        T[r * 64 + lane] = src[(size_t)r * PLN + lane];
    }
    __syncthreads();

    // ---- chunk-20 sweep from LDS (wave = 64 cols x 1 chunk; conflict-free:
    //      fixed row -> lanes span banks 0..31 twice = 2-way broadcast-free)
    const int c = lane, n0 = wv * 20;
    float st = 0.f;
    #pragma unroll
    for (int s = 0; s < KW; ++s) {         // causal warm-up (wraps)
        int r = n0 - KW + s; if (r < 0) r += NAX;
        st = fmaf(z, st, 6.0f * T[r * 64 + c]);
    }
    float f[20];
    #pragma unroll
    for (int s = 0; s < 20; ++s) {         // causal outputs (never wraps)
        st = fmaf(z, st, 6.0f * T[(n0 + s) * 64 + c]);
        f[s] = st;
    }
    float Ta = 0.f, zp = z;                // T-trick: c-(n0+20) = -T
    #pragma unroll
    for (int k = 0; k < KW; ++k) {
        int r = n0 + 20 + k; if (r >= NAX) r -= NAX;
        st = fmaf(z, st, 6.0f * T[r * 64 + c]);
        Ta = fmaf(zp, st, Ta);
        zp *= z;                           // constant-folds under unroll
    }
    float sm = -Ta;                        // anticausal sweep, direct store
    #pragma unroll
    for (int s = 19; s >= 0; --s) {
        sm = z * (sm - f[s]);
        dst[(size_t)(n0 + s) * PLN + c] = sm;
    }
}

// ---------------- Kernel B: fused axes 3+4, 40-row slab (VERBATIM R9) -------
__device__ __forceinline__ int swz(int r, int c) {
    return r * NAX + (c ^ (r & 31));
}

__global__ __launch_bounds__(320, 6)
void slab_d3d4(const float* __restrict__ src, float* __restrict__ dst)
{
    __shared__ float Y[40 * NAX];        // 25.6 KB exchange buffer
    const float z = ZP;
    const int tid = threadIdx.x;         // 0..319

    // XCD-coherent decode: all 4 slabs of plane p share blockIdx%8
    const int b   = blockIdx.x;
    const int q   = (b >> 3) & 3;        // slab 0..3
    const int p   = ((b >> 5) << 3) + (b & 7);   // plane 0..959
    const int R0  = 40 * q;
    const float* pin  = src + (size_t)p * PLN;
    float*       pout = dst + (size_t)p * PLN;

    float f[20];

    // ---- d3: thread (c, h) -> rows R0+20h .. R0+20h+19, column c -----------
    {
        const int c  = tid % NAX;
        const int h  = tid / NAX;        // 0..1
        const int n0 = R0 + 20 * h;
        float st = 0.0f;
        #pragma unroll
        for (int s = 0; s < KW; ++s) {   // causal warm-up (wraps)
            int r = n0 - KW + s; if (r < 0) r += NAX;
            st = fmaf(z, st, 6.0f * pin[r * NAX + c]);
        }
        #pragma unroll
        for (int s = 0; s < 20; ++s) {   // causal outputs
            st = fmaf(z, st, 6.0f * pin[(n0 + s) * NAX + c]);
            f[s] = st;
        }
        float Ta = 0.0f, zp = z;         // T-trick: c-(n0+20) = -T
        #pragma unroll
        for (int k = 0; k < KW; ++k) {
            int r = n0 + 20 + k; if (r >= NAX) r -= NAX;
            st = fmaf(z, st, 6.0f * pin[r * NAX + c]);
            Ta = fmaf(zp, st, Ta);
            zp *= z;                     // constant-folds under unroll
        }
        float sm = -Ta;
        #pragma unroll
        for (int s = 19; s >= 0; --s) { sm = z * (sm - f[s]); f[s] = sm; }

        const int lr0 = 20 * h;          // publish slab rows (local 0..39)
        #pragma unroll
        for (int s = 0; s < 20; ++s)
            Y[swz(lr0 + s, c)] = f[s];
    }
    __syncthreads();

    // ---- d4: thread (rr, mq); remap rr=tid>>3 spreads banks ----------------
    {
        const int rr = tid >> 3;         // 0..39
        const int mq = tid & 7;          // 0..7
        const int m0 = 20 * mq;
        float st = 0.0f;
        #pragma unroll
        for (int s = 0; s < KW; ++s) {
            int cc = m0 - KW + s; if (cc < 0) cc += NAX;
            st = fmaf(z, st, 6.0f * Y[swz(rr, cc)]);
        }
        #pragma unroll
        for (int s = 0; s < 20; ++s) {
            st = fmaf(z, st, 6.0f * Y[swz(rr, m0 + s)]);
            f[s] = st;
        }
        float Ta = 0.0f, zp = z;
        #pragma unroll
        for (int k = 0; k < KW; ++k) {
            int cc = m0 + 20 + k; if (cc >= NAX) cc -= NAX;
            st = fmaf(z, st, 6.0f * Y[swz(rr, cc)]);
            Ta = fmaf(zp, st, Ta);
            zp *= z;
        }
        float sm = -Ta;
        #pragma unroll
        for (int s = 19; s >= 0; --s) { sm = z * (sm - f[s]); f[s] = sm; }

        __syncthreads();                 // ALL Y reads done before overwrite
        #pragma unroll
        for (int s = 0; s < 20; ++s)
            Y[swz(rr, m0 + s)] = f[s];
    }
    __syncthreads();

    // ---- coalesced NT store (out never re-read: keep it out of L3) ---------
    #pragma unroll
    for (int k = 0; k < 20; ++k) {
        const int idx = tid + 320 * k;
        const int lr  = idx / NAX;
        const int c   = idx - lr * NAX;
        __builtin_nontemporal_store(Y[swz(lr, c)], &pout[(R0 + lr) * NAX + c]);
    }
}

// ---------------- Fallback: R3-validated in-place full-plane kernel ---------
__global__ __launch_bounds__(640, 2)
void pass_d3d4(float* __restrict__ buf)
{
    __shared__ float P[PLN];
    const float z = ZP;
    const int tid = threadIdx.x;
    float* plane = buf + (size_t)blockIdx.x * PLN;

    const int c  = tid % NAX;
    const int tq = tid / NAX;
    const int n0 = tq * 40;

    #pragma unroll
    for (int k = 0; k < 40; ++k) {
        const int r = 4 * k + tq;
        P[swz(r, c)] = plane[r * NAX + c];
    }
    __syncthreads();

    float f[40];
    {
        float st = 0.0f;
        #pragma unroll
        for (int s = 0; s < KW; ++s) {
            int r = n0 - KW + s; if (r < 0) r += NAX;
            st = fmaf(z, st, 6.0f * P[swz(r, c)]);
        }
        #pragma unroll
        for (int s = 0; s < 40; ++s) {
            st = fmaf(z, st, 6.0f * P[swz(n0 + s, c)]);
            f[s] = st;
        }
        __syncthreads();
        #pragma unroll
        for (int s = 0; s < 40; ++s) P[swz(n0 + s, c)] = f[s];
        __syncthreads();
        float sm = 0.0f;
        #pragma unroll
        for (int s = KW - 1; s >= 0; --s) {
            int r = n0 + 40 + s; if (r >= NAX) r -= NAX;
            sm = z * (sm - P[swz(r, c)]);
        }
        __syncthreads();
        #pragma unroll
        for (int s = 39; s >= 0; --s) { sm = z * (sm - f[s]); P[swz(n0 + s, c)] = sm; }
        __syncthreads();
    }
    {
        const int rr = c;
        float st = 0.0f;
        #pragma unroll
        for (int s = 0; s < KW; ++s) {
            int cc = n0 - KW + s; if (cc < 0) cc += NAX;
            st = fmaf(z, st, 6.0f * P[swz(rr, cc)]);
        }
        #pragma unroll
        for (int s = 0; s < 40; ++s) {
            st = fmaf(z, st, 6.0f * P[swz(rr, n0 + s)]);
            f[s] = st;
        }
        __syncthreads();
        #pragma unroll
        for (int s = 0; s < 40; ++s) P[swz(rr, n0 + s)] = f[s];
        __syncthreads();
        float sm = 0.0f;
        #pragma unroll
        for (int s = KW - 1; s >= 0; --s) {
            int cc = n0 + 40 + s; if (cc >= NAX) cc -= NAX;
            sm = z * (sm - P[swz(rr, cc)]);
        }
        __syncthreads();
        #pragma unroll
        for (int s = 39; s >= 0; --s) { sm = z * (sm - f[s]); P[swz(rr, n0 + s)] = sm; }
        __syncthreads();
    }
    #pragma unroll
    for (int k = 0; k < 40; ++k) {
        const int r = 4 * k + tq;
        plane[r * NAX + c] = P[swz(r, c)];
    }
}

extern "C" void kernel_launch(void* const* d_in, const int* in_sizes, int n_in,
                              void* d_out, int out_size, void* d_ws, size_t ws_size,
                              hipStream_t stream) {
    (void)in_sizes; (void)n_in; (void)out_size;
    const float* x = (const float*)d_in[0];
    float* out = (float*)d_out;
    float* ws  = (float*)d_ws;

    const size_t need = (size_t)6 * VOL * sizeof(float);   // 98.3 MB intermediate
    if (ws_size >= need) {
        k_d2s    <<<2400, 512, 0, stream>>>(x, ws);    // in -> ws
        slab_d3d4<<<3840, 320, 0, stream>>>(ws, out);  // ws -> out (disjoint)
    } else {
        k_d2s    <<<2400, 512, 0, stream>>>(x, out);
        pass_d3d4<<<960,  640, 0, stream>>>(out);      // validated fallback
    }
}

// Round 12
// 66.296 us; speedup vs baseline: 2.1773x; 1.0680x over previous
//
#include <hip/hip_runtime.h>

// Cubic B-spline prefilter (Unser), periodic, axes 2,3,4 of (2,3,160,160,160) fp32.
//
// Pipeline (R10 winner, 70.8 us) with VALU-diet (R11):
//   - SCALE-FOLDING: recursions run UNSCALED (u = x + z u, v = z(v - u)) through
//     all three axes; final NT store multiplies by 6^3 = 216 once. Removes the
//     6.0f* mul on every load (~150 VALU/thread pipeline-wide).
//   - NO-WRAP SPLIT: chunk starts n0 in {0,20,..,140} -> warm range [n0-16,n0)
//     and tail range [n0+20,n0+36) wrap fully or not at all, never mid-range.
//     One select for the base, inner loops use base + literal offsets (no
//     per-iteration compare+select; strength-reduced addressing).
//   k_d2s     : axis-2 via LDS-staged [160x64] tile (40 KB), 512 thr, 1 barrier,
//               chunk-20 register sweeps, direct stores. x -> ws (unscaled).
//   slab_d3d4 : axes 3+4 fused, 40x160 slab, T-trick, d4 remap rr=tid>>3,
//               XCD-coherent block map, NT final store (x216). ws -> out.
// Fallback (ws too small): R3-validated in-place full-plane kernel.

#define NAX   160
#define PLN   25600      // 160*160
#define VOL   4096000    // 160*PLN
#define ZP    (-0.26794919243112270647f)   // sqrt(3)-2
#define KW    16         // truncated warm-up (z^16 ~ 7.4e-10)
#define SCALE 216.0f     // 6^3, applied once at the final store

// ---------------- Kernel A: axis-2, LDS-staged full-axis tile ---------------
__global__ __launch_bounds__(512, 6)
void k_d2s(const float* __restrict__ in, float* __restrict__ out)
{
    __shared__ float T[NAX * 64];          // 40 KB, layout [row][64]
    const float z = ZP;
    const int t    = threadIdx.x;
    const int lane = t & 63, wv = t >> 6;  // col-in-tile, wave(=chunk) 0..7
    const int g  = blockIdx.x;             // 0..2399
    const int v  = g / 400;                // volume (b,c) 0..5
    const int i0 = (g - v * 400) * 64;     // col base in flattened (d3,d4)
    const float* src = in  + (size_t)v * VOL + i0;
    float*       dst = out + (size_t)v * VOL + i0;

    // ---- load tile: wave wv covers rows wv, wv+8, ..., each 256 B contiguous
    #pragma unroll
    for (int k = 0; k < 20; ++k) {
        const int r = wv + 8 * k;
        T[r * 64 + lane] = src[(size_t)r * PLN + lane];
    }
    __syncthreads();

    const int c = lane, n0 = wv * 20;
    const int wb = (n0 == 0) ? (NAX - KW) : (n0 - KW);     // warm base (no mid-wrap)
    const int tb = (n0 == NAX - 20) ? 0 : (n0 + 20);       // tail base (no mid-wrap)

    const float* Tw = T + wb * 64 + c;
    float st = 0.f;
    #pragma unroll
    for (int s = 0; s < KW; ++s)           // causal warm-up
        st = fmaf(z, st, Tw[s * 64]);
    const float* Tm = T + n0 * 64 + c;
    float f[20];
    #pragma unroll
    for (int s = 0; s < 20; ++s) {         // causal outputs
        st = fmaf(z, st, Tm[s * 64]);
        f[s] = st;
    }
    const float* Tt = T + tb * 64 + c;
    float Ta = 0.f, zp = z;                // T-trick: v(n0+20) = -Ta
    #pragma unroll
    for (int k = 0; k < KW; ++k) {
        st = fmaf(z, st, Tt[k * 64]);
        Ta = fmaf(zp, st, Ta);
        zp *= z;                           // constant-folds under unroll
    }
    float sm = -Ta;                        // anticausal sweep, direct store
    #pragma unroll
    for (int s = 19; s >= 0; --s) {
        sm = z * (sm - f[s]);
        dst[(size_t)(n0 + s) * PLN + c] = sm;   // unscaled -> ws
    }
}

// ---------------- Kernel B: fused axes 3+4, 40-row slab ---------------------
__device__ __forceinline__ int swz(int r, int c) {
    return r * NAX + (c ^ (r & 31));
}

__global__ __launch_bounds__(320, 6)
void slab_d3d4(const float* __restrict__ src, float* __restrict__ dst)
{
    __shared__ float Y[40 * NAX];        // 25.6 KB exchange buffer
    const float z = ZP;
    const int tid = threadIdx.x;         // 0..319

    // XCD-coherent decode: all 4 slabs of plane p share blockIdx%8
    const int b   = blockIdx.x;
    const int q   = (b >> 3) & 3;        // slab 0..3
    const int p   = ((b >> 5) << 3) + (b & 7);   // plane 0..959
    const int R0  = 40 * q;
    const float* pin  = src + (size_t)p * PLN;
    float*       pout = dst + (size_t)p * PLN;

    float f[20];

    // ---- d3: thread (c, h) -> rows R0+20h .. R0+20h+19, column c -----------
    {
        const int c  = tid % NAX;
        const int h  = tid / NAX;        // 0..1
        const int n0 = R0 + 20 * h;
        const int wb = (n0 == 0) ? (NAX - KW) : (n0 - KW);
        const int tb = (n0 == NAX - 20) ? 0 : (n0 + 20);

        const float* pw = pin + wb * NAX + c;
        float st = 0.0f;
        #pragma unroll
        for (int s = 0; s < KW; ++s)     // causal warm-up
            st = fmaf(z, st, pw[s * NAX]);
        const float* pm = pin + n0 * NAX + c;
        #pragma unroll
        for (int s = 0; s < 20; ++s) {   // causal outputs
            st = fmaf(z, st, pm[s * NAX]);
            f[s] = st;
        }
        const float* pt = pin + tb * NAX + c;
        float Ta = 0.0f, zp = z;         // T-trick
        #pragma unroll
        for (int k = 0; k < KW; ++k) {
            st = fmaf(z, st, pt[k * NAX]);
            Ta = fmaf(zp, st, Ta);
            zp *= z;
        }
        float sm = -Ta;
        #pragma unroll
        for (int s = 19; s >= 0; --s) { sm = z * (sm - f[s]); f[s] = sm; }

        const int lr0 = 20 * h;          // publish slab rows (local 0..39)
        #pragma unroll
        for (int s = 0; s < 20; ++s)
            Y[swz(lr0 + s, c)] = f[s];
    }
    __syncthreads();

    // ---- d4: thread (rr, mq); remap rr=tid>>3 spreads banks ----------------
    {
        const int rr = tid >> 3;         // 0..39
        const int mq = tid & 7;          // 0..7
        const int m0 = 20 * mq;
        const int wb = (m0 == 0) ? (NAX - KW) : (m0 - KW);
        const int tb = (m0 == NAX - 20) ? 0 : (m0 + 20);
        const int xo = rr & 31;
        const float* Yr = Y + rr * NAX;

        float st = 0.0f;
        #pragma unroll
        for (int s = 0; s < KW; ++s)
            st = fmaf(z, st, Yr[(wb + s) ^ xo]);
        #pragma unroll
        for (int s = 0; s < 20; ++s) {
            st = fmaf(z, st, Yr[(m0 + s) ^ xo]);
            f[s] = st;
        }
        float Ta = 0.0f, zp = z;
        #pragma unroll
        for (int k = 0; k < KW; ++k) {
            st = fmaf(z, st, Yr[(tb + k) ^ xo]);
            Ta = fmaf(zp, st, Ta);
            zp *= z;
        }
        float sm = -Ta;
        #pragma unroll
        for (int s = 19; s >= 0; --s) { sm = z * (sm - f[s]); f[s] = sm; }

        __syncthreads();                 // ALL Y reads done before overwrite
        float* Yw = Y + rr * NAX;
        #pragma unroll
        for (int s = 0; s < 20; ++s)
            Yw[(m0 + s) ^ xo] = f[s];
    }
    __syncthreads();

    // ---- coalesced NT store, x216 (undo the three folded 1/6 scalings) -----
    #pragma unroll
    for (int k = 0; k < 20; ++k) {
        const int idx = tid + 320 * k;
        const int lr  = idx / NAX;
        const int c   = idx - lr * NAX;
        __builtin_nontemporal_store(SCALE * Y[swz(lr, c)],
                                    &pout[(R0 + lr) * NAX + c]);
    }
}

// ---------------- Fallback: in-place full-plane kernel (R3, with x216) ------
__global__ __launch_bounds__(640, 2)
void pass_d3d4(float* __restrict__ buf)
{
    __shared__ float P[PLN];
    const float z = ZP;
    const int tid = threadIdx.x;
    float* plane = buf + (size_t)blockIdx.x * PLN;

    const int c  = tid % NAX;
    const int tq = tid / NAX;
    const int n0 = tq * 40;

    #pragma unroll
    for (int k = 0; k < 40; ++k) {
        const int r = 4 * k + tq;
        P[swz(r, c)] = plane[r * NAX + c];
    }
    __syncthreads();

    float f[40];
    {
        float st = 0.0f;
        #pragma unroll
        for (int s = 0; s < KW; ++s) {
            int r = n0 - KW + s; if (r < 0) r += NAX;
            st = fmaf(z, st, P[swz(r, c)]);
        }
        #pragma unroll
        for (int s = 0; s < 40; ++s) {
            st = fmaf(z, st, P[swz(n0 + s, c)]);
            f[s] = st;
        }
        __syncthreads();
        #pragma unroll
        for (int s = 0; s < 40; ++s) P[swz(n0 + s, c)] = f[s];
        __syncthreads();
        float sm = 0.0f;
        #pragma unroll
        for (int s = KW - 1; s >= 0; --s) {
            int r = n0 + 40 + s; if (r >= NAX) r -= NAX;
            sm = z * (sm - P[swz(r, c)]);
        }
        __syncthreads();
        #pragma unroll
        for (int s = 39; s >= 0; --s) { sm = z * (sm - f[s]); P[swz(n0 + s, c)] = sm; }
        __syncthreads();
    }
    {
        const int rr = c;
        float st = 0.0f;
        #pragma unroll
        for (int s = 0; s < KW; ++s) {
            int cc = n0 - KW + s; if (cc < 0) cc += NAX;
            st = fmaf(z, st, P[swz(rr, cc)]);
        }
        #pragma unroll
        for (int s = 0; s < 40; ++s) {
            st = fmaf(z, st, P[swz(rr, n0 + s)]);
            f[s] = st;
        }
        __syncthreads();
        #pragma unroll
        for (int s = 0; s < 40; ++s) P[swz(rr, n0 + s)] = f[s];
        __syncthreads();
        float sm = 0.0f;
        #pragma unroll
        for (int s = KW - 1; s >= 0; --s) {
            int cc = n0 + 40 + s; if (cc >= NAX) cc -= NAX;
            sm = z * (sm - P[swz(rr, cc)]);
        }
        __syncthreads();
        #pragma unroll
        for (int s = 39; s >= 0; --s) { sm = z * (sm - f[s]); P[swz(rr, n0 + s)] = sm; }
        __syncthreads();
    }
    #pragma unroll
    for (int k = 0; k < 40; ++k) {
        const int r = 4 * k + tq;
        plane[r * NAX + c] = SCALE * P[swz(r, c)];
    }
}

extern "C" void kernel_launch(void* const* d_in, const int* in_sizes, int n_in,
                              void* d_out, int out_size, void* d_ws, size_t ws_size,
                              hipStream_t stream) {
    (void)in_sizes; (void)n_in; (void)out_size;
    const float* x = (const float*)d_in[0];
    float* out = (float*)d_out;
    float* ws  = (float*)d_ws;

    const size_t need = (size_t)6 * VOL * sizeof(float);   // 98.3 MB intermediate
    if (ws_size >= need) {
        k_d2s    <<<2400, 512, 0, stream>>>(x, ws);    // in -> ws (unscaled)
        slab_d3d4<<<3840, 320, 0, stream>>>(ws, out);  // ws -> out (x216 at store)
    } else {
        k_d2s    <<<2400, 512, 0, stream>>>(x, out);
        pass_d3d4<<<960,  640, 0, stream>>>(out);      // fallback (x216 at store)
    }
}